// Round 1
// baseline (303.005 us; speedup 1.0000x reference)
//
#include <hip/hip_runtime.h>
#include <math.h>

#define BATCH 4
#define TU 4096
#define TM 2048
#define DM 1024
#define FF 2048          // 2*D
#define KB 4             // max births
#define NROWS (BATCH*KB) // 16
#define OUT_TM (TM+KB)   // 2052

// ---------------- kernel 1: row means of r_emer_acc + copy o_macro -> out ----
__global__ __launch_bounds__(256) void k_mean_copy(
    const float* __restrict__ r_emer, const float* __restrict__ o_macro,
    float* __restrict__ micro_res, float* __restrict__ out)
{
    const int tid  = threadIdx.x;
    const int lane = tid & 63;
    const int wave = tid >> 6;
    const int row  = blockIdx.x * 4 + wave;          // 0 .. 16383 (b*TU + t)

    // Part A: mean over 2048 floats (one wave per row), coalesced float4
    const float4* rp = (const float4*)(r_emer + (size_t)row * FF);
    float s = 0.0f;
    #pragma unroll
    for (int j = 0; j < 8; ++j) {
        float4 v = rp[lane + 64 * j];
        s += v.x + v.y + v.z + v.w;
    }
    #pragma unroll
    for (int off = 32; off >= 1; off >>= 1)
        s += __shfl_down(s, off, 64);
    if (lane == 0) micro_res[row] = s * (1.0f / 2048.0f);

    // Part B: copy o_macro into out (batch-strided for the +4 child rows)
    const float4* src = (const float4*)o_macro;
    float4* dst = (float4*)out;
    const int NF4       = BATCH * TM * DM / 4;   // 2097152
    const int PER_BATCH = TM * DM / 4;           // 524288 (2^19)
    const int DST_BATCH = OUT_TM * DM / 4;       // 525312
    for (int e = blockIdx.x * 256 + tid; e < NF4; e += gridDim.x * 256) {
        int b = e >> 19;
        int q = e & (PER_BATCH - 1);
        dst[b * DST_BATCH + q] = src[e];
    }
}

// ---------------- kernel 2: per-batch top-4 pair scores ----------------------
__global__ __launch_bounds__(256) void k_topk(
    const float* __restrict__ micro_res,
    const float* __restrict__ threshold_bias,
    int* __restrict__ topk_idx, float* __restrict__ topk_val)
{
    __shared__ float res[TU];     // 16 KB
    __shared__ float rv[256];
    __shared__ int   ri[256];
    __shared__ int   sel[KB];
    __shared__ float selv[KB];

    const int b = blockIdx.x, tid = threadIdx.x;
    const float* mr = micro_res + b * TU;
    for (int i = tid; i < TU; i += 256) res[i] = mr[i];
    __syncthreads();

    const float thr = 0.45f + tanhf(threshold_bias[0]) * 0.2f;

    for (int p = 0; p < KB; ++p) {
        float bv = -1.0f; int bi = 0x7fffffff;
        for (int t = tid; t < TU - 1; t += 256) {
            bool skip = false;
            for (int q = 0; q < p; ++q) if (sel[q] == t) skip = true;
            if (skip) continue;
            float pr = (res[t] + res[t + 1]) * 0.5f;
            float sc = pr > thr ? pr : 0.0f;
            if (sc > bv || (sc == bv && t < bi)) { bv = sc; bi = t; }
        }
        rv[tid] = bv; ri[tid] = bi;
        __syncthreads();
        for (int s = 128; s >= 1; s >>= 1) {
            if (tid < s) {
                float ov = rv[tid + s]; int oi = ri[tid + s];
                if (ov > rv[tid] || (ov == rv[tid] && oi < ri[tid])) {
                    rv[tid] = ov; ri[tid] = oi;
                }
            }
            __syncthreads();
        }
        if (tid == 0) { sel[p] = ri[0]; selv[p] = rv[0]; }
        __syncthreads();
    }
    if (tid < KB) {
        topk_idx[b * KB + tid] = sel[tid];
        topk_val[b * KB + tid] = selv[tid];
    }
}

// ---------------- kernel 3: child_raw[r][d] = combined[r] . W[d] -------------
__global__ __launch_bounds__(256) void k_child(
    const float* __restrict__ o_micro, const float* __restrict__ W,
    const int* __restrict__ topk_idx, float* __restrict__ child_raw)
{
    const int d   = blockIdx.x;       // 0..1023
    const int tid = threadIdx.x;
    const int lane = tid & 63;
    const int wave = tid >> 6;
    const int f0  = tid * 8;          // thread's slice of the 2048-long dot

    __shared__ int sidx[NROWS];
    if (tid < NROWS) sidx[tid] = topk_idx[tid];
    __syncthreads();

    const float4* wp = (const float4*)(W + (size_t)d * FF + f0);
    const float4 w0 = wp[0], w1 = wp[1];

    float acc[NROWS];
    #pragma unroll
    for (int r = 0; r < NROWS; ++r) {
        const int bb  = r >> 2;
        const int idx = sidx[r];
        const float* srcrow;
        int fo;
        if (f0 < DM) { srcrow = o_micro + ((size_t)bb * TU + idx) * DM;     fo = f0; }
        else         { srcrow = o_micro + ((size_t)bb * TU + idx + 1) * DM; fo = f0 - DM; }
        const float4* cp = (const float4*)(srcrow + fo);
        float4 c0 = cp[0], c1 = cp[1];
        acc[r] = c0.x * w0.x + c0.y * w0.y + c0.z * w0.z + c0.w * w0.w
               + c1.x * w1.x + c1.y * w1.y + c1.z * w1.z + c1.w * w1.w;
    }

    // wave shuffle reduce each of the 16 accumulators
    #pragma unroll
    for (int r = 0; r < NROWS; ++r) {
        float v = acc[r];
        #pragma unroll
        for (int off = 32; off >= 1; off >>= 1)
            v += __shfl_down(v, off, 64);
        acc[r] = v;
    }
    __shared__ float part[4][NROWS];
    if (lane == 0) {
        #pragma unroll
        for (int r = 0; r < NROWS; ++r) part[wave][r] = acc[r];
    }
    __syncthreads();
    if (tid < NROWS)
        child_raw[(size_t)tid * DM + d] =
            part[0][tid] + part[1][tid] + part[2][tid] + part[3][tid];
}

// ---------------- kernel 4: gate + masked write + n_births -------------------
__global__ __launch_bounds__(256) void k_gate(
    const float* __restrict__ child_raw, const float* __restrict__ w_gate,
    const float* __restrict__ b_gate, const float* __restrict__ topk_val,
    float* __restrict__ out)
{
    const int row = blockIdx.x;     // 0..15  (b*4 + k)
    const int b = row >> 2, k = row & 3;
    const int tid = threadIdx.x;
    const int lane = tid & 63, wave = tid >> 6;

    const float4* cp = (const float4*)(child_raw + (size_t)row * DM);
    const float4* wp = (const float4*)w_gate;
    float4 c = cp[tid], w = wp[tid];
    float dotp = c.x * w.x + c.y * w.y + c.z * w.z + c.w * w.w;

    #pragma unroll
    for (int off = 32; off >= 1; off >>= 1)
        dotp += __shfl_down(dotp, off, 64);

    __shared__ float ps[4];
    __shared__ float scale_s;
    if (lane == 0) ps[wave] = dotp;
    __syncthreads();
    if (tid == 0) {
        float dsum = ps[0] + ps[1] + ps[2] + ps[3] + b_gate[0];
        float gate = 1.0f / (1.0f + expf(-dsum));
        float mask = topk_val[row] > 0.0f ? 1.0f : 0.0f;
        scale_s = gate * mask;
    }
    __syncthreads();

    const float s = scale_s;
    float4 o; o.x = c.x * s; o.y = c.y * s; o.z = c.z * s; o.w = c.w * s;
    float4* op = (float4*)(out + ((size_t)b * OUT_TM + TM + k) * DM);
    op[tid] = o;

    if (row == 0 && tid == 0) {
        int n = 0;
        for (int i = 0; i < NROWS; ++i) n += (topk_val[i] > 0.0f) ? 1 : 0;
        out[(size_t)BATCH * OUT_TM * DM] = (float)n;   // n_births
    }
}

extern "C" void kernel_launch(void* const* d_in, const int* in_sizes, int n_in,
                              void* d_out, int out_size, void* d_ws, size_t ws_size,
                              hipStream_t stream) {
    const float* o_micro   = (const float*)d_in[0];
    const float* o_macro   = (const float*)d_in[1];
    const float* r_emer    = (const float*)d_in[2];
    // d_in[3] chunk_size — unused by the reference
    const float* W_vesica  = (const float*)d_in[4];
    const float* w_gate    = (const float*)d_in[5];
    const float* b_gate    = (const float*)d_in[6];
    const float* thr_bias  = (const float*)d_in[7];
    float* out = (float*)d_out;

    // workspace layout (floats)
    float* wsf       = (float*)d_ws;
    float* micro_res = wsf;                    // 16384 floats
    int*   topk_idx  = (int*)(wsf + 16384);    // 16 ints
    float* topk_val  = wsf + 16400;            // 16 floats
    float* child_raw = wsf + 16416;            // 16384 floats

    k_mean_copy<<<4096, 256, 0, stream>>>(r_emer, o_macro, micro_res, out);
    k_topk<<<BATCH, 256, 0, stream>>>(micro_res, thr_bias, topk_idx, topk_val);
    k_child<<<DM, 256, 0, stream>>>(o_micro, W_vesica, topk_idx, child_raw);
    k_gate<<<NROWS, 256, 0, stream>>>(child_raw, w_gate, b_gate, topk_val, out);
}